// Round 25
// baseline (37.631 us; speedup 1.0000x reference)
//
#include <hip/hip_runtime.h>
#include <math.h>

#define CDIM   862
#define NRANK  8
#define KW     7
#define ROWS_PER_BLOCK 4
#define THREADS (ROWS_PER_BLOCK * 64)
#define LN_EPS 1e-5f
#define NTILE  7             // 7 quad-tiles x 128 elements cover [-1,894] >= [0,861]
#define XH_LEN 912           // shorts: [0..3]=x[-4..-1]=0, [4+i]=bf16(x[i]), zeros to 911

typedef __attribute__((ext_vector_type(8)))  short bf16x8;
typedef __attribute__((ext_vector_type(16))) float f32x16;

static __device__ __forceinline__ unsigned rne_bf16(float f) {
    const unsigned u = __float_as_uint(f);
    return (u + 0x7FFFu + ((u >> 16) & 1u)) >> 16;   // round-to-nearest-even
}

// v_exp_f32 IS 2^x on gfx950 (r20-validated). Fallback exact.
#if __has_builtin(__builtin_amdgcn_exp2f)
#define EXP2F(x) __builtin_amdgcn_exp2f(x)
#else
#define EXP2F(x) __expf((x) * 0.69314718055994530942f)
#endif

// One wave = one row. Shuffle-free quad-tile MFMA (r23-validated mapping,
// absmax 0.03125). THIS ROUND: y LIVES IN REGISTERS -- the per-tile
// LDS y read-modify-write and the f32 sxy buffer are gone entirely.
//   - lane's 14 owned f32 x-values prefetched from global during staging
//     (dense permuted pattern: per tile the wave's addresses cover
//     [128s-1,128s+62] densely -> full sector coalescing, L1-hot)
//   - tile loop: ds_read window -> MFMA -> dp8 -> y_reg = xv_reg + h
//     (no LDS in the chain after the window read)
//   - epilogue: normalize from registers, store straight to global
//     (dense permuted per instruction), gamma/beta loaded per element
//   - LDS/block 21.5 KB -> 7.3 KB (bf16 windows only)
// Per-lane arithmetic order unchanged -> absmax must stay exactly 0.03125.
__global__ __launch_bounds__(THREADS) void cvmc_kernel(
    const float* __restrict__ x,
    const float* __restrict__ Wup,
    const float* __restrict__ bup,
    const float* __restrict__ Wdown,
    const float* __restrict__ bdown,
    const float* __restrict__ gamma,
    const float* __restrict__ beta,
    float* __restrict__ out)
{
    const int lane = threadIdx.x & 63;
    const int wv   = threadIdx.x >> 6;
    const int row  = blockIdx.x * ROWS_PER_BLOCK + wv;

    __shared__ short sxh[ROWS_PER_BLOCK][XH_LEN];

    const int hh  = lane >> 5;
    const int l31 = lane & 31;

    // all 8 rank weights per lane (wave-uniform -> SGPR)
    float bu8[NRANK], wd8[NRANK];
#pragma unroll
    for (int q = 0; q < NRANK; ++q) {
        bu8[q] = bup[q];
        wd8[q] = Wdown[q];
    }

    // ---- A fragment: row = l31, k-slot k = 8*hh + j (r23-verified mapping) ----
    bf16x8 afrag;
    {
        const int  rr   = (l31 & 3) + 4 * ((l31 >> 3) & 1);
        const int  sft  = (l31 >> 2) & 1;
        const bool use  = ((l31 >> 4) == hh);
#pragma unroll
        for (int j = 0; j < 8; ++j) {
            const int tap = j - sft;
            float wvv = (use && tap >= 0 && tap < KW) ? Wup[rr * KW + tap] : 0.0f;
            afrag[j] = (short)(rne_bf16(wvv) & 0xFFFFu);
        }
    }

    // ---- C operand: bias; rank of reg q is q&7 for every lane ----
    f32x16 cin;
#pragma unroll
    for (int i = 0; i < 16; ++i) cin[i] = bu8[i & 7];

    // ---- stage row: sxh = bf16(RNE) windows; pads zeroed ----
    const float* __restrict__ xr = x + (size_t)row * CDIM;
    {
        const float2* __restrict__ xr2 = reinterpret_cast<const float2*>(xr);
        unsigned* xhW = reinterpret_cast<unsigned*>(&sxh[wv][0]);
#pragma unroll
        for (int qq = 0; qq < 7; ++qq) {
            const int i = lane + 64 * qq;               // float2 pair index
            if (i < CDIM / 2) {
                float2 v = xr2[i];
                xhW[2 + i] = rne_bf16(v.x) | (rne_bf16(v.y) << 16);
            }
        }
        if (lane < 2)        xhW[lane] = 0u;            // shorts 0..3 = x[-4..-1]
        else if (lane < 25)  xhW[431 + lane] = 0u;      // dwords 433..455 zero
    }

    // ---- prefetch this lane's 14 owned f32 x-values into registers ----
    float xv0[NTILE], xv1[NTILE];
#pragma unroll
    for (int s = 0; s < NTILE; ++s) {
        const int e0 = 128 * s + 2 * l31 - 1 + hh;
        const int e1 = e0 + 64;
        const int c0 = e0 < 0 ? 0 : (e0 >= CDIM ? CDIM - 1 : e0);
        const int c1 = e1 >= CDIM ? CDIM - 1 : e1;
        xv0[s] = xr[c0];
        xv1[s] = xr[c1];
    }
    // wave-private LDS slice; same-wave DS ops complete in issue order -> no barrier

    // gelu(t) ~ t*sigmoid(1.5957691 t + 0.0713548 t^3); u = 1 + 2^z (log2e folded)
    const float C1 = -0.0713548162f * 1.44269504088896340736f;
    const float C0 = -1.5957691216f * 1.44269504088896340736f;

    const unsigned* xhD = reinterpret_cast<const unsigned*>(&sxh[wv][0]);

    // full 8-rank GELU + down-proj, lane-local (rank-paired rcp as r15-r24)
    auto dp8 = [&](const float* t) -> float {
        float u[NRANK];
#pragma unroll
        for (int r = 0; r < NRANK; ++r) {
            const float z = t[r] * fmaf(t[r] * t[r], C1, C0);
            u[r] = 1.0f + EXP2F(z);
        }
        float h = 0.0f;
#pragma unroll
        for (int rp = 0; rp < NRANK / 2; ++rp) {
            const float ua = u[2 * rp], ub = u[2 * rp + 1];
            const float rr = __builtin_amdgcn_rcpf(ua * ub);
            float n = (wd8[2 * rp] * t[2 * rp]) * ub;
            n = fmaf(wd8[2 * rp + 1] * t[2 * rp + 1], ua, n);
            h = fmaf(n, rr, h);
        }
        return h;
    };

    float y0[NTILE], y1[NTILE];
    float sum = 0.0f, sumsq = 0.0f;

#pragma unroll
    for (int s = 0; s < NTILE; ++s) {
        // this lane's window: 4 aligned dwords (8 bf16) -- its k-half of column l31
        const int w = 64 * s + lane;
        union { unsigned u[4]; bf16x8 v; } bfr;
        bfr.u[0] = xhD[w];
        bfr.u[1] = xhD[w + 1];
        bfr.u[2] = xhD[w + 2];
        bfr.u[3] = xhD[w + 3];

        f32x16 d = __builtin_amdgcn_mfma_f32_32x32x16_bf16(afrag, bfr.v, cin, 0, 0, 0);

        float t0[NRANK], t1[NRANK];
#pragma unroll
        for (int r = 0; r < NRANK; ++r) { t0[r] = d[r]; t1[r] = d[8 + r]; }

        const float h0 = dp8(t0);      // all 8 ranks of eS0 -- lane-local
        const float h1 = dp8(t1);      // all 8 ranks of eS0+64

        const int eS0 = 128 * s + 2 * l31 - 1 + hh;
        const int eS1 = eS0 + 64;

        const float a = xv0[s] + h0;   // residual from REGISTER (no LDS)
        const float b = xv1[s] + h1;
        y0[s] = a;
        y1[s] = b;
        if ((unsigned)eS0 < CDIM) { sum += a; sumsq = fmaf(a, a, sumsq); }
        if ((unsigned)eS1 < CDIM) { sum += b; sumsq = fmaf(b, b, sumsq); }
    }

    // in-wave butterfly: every lane ends with the row totals
#pragma unroll
    for (int off = 1; off < 64; off <<= 1) {
        sum   += __shfl_xor(sum, off, 64);
        sumsq += __shfl_xor(sumsq, off, 64);
    }

    const float inv  = 1.0f / (float)CDIM;
    const float mu   = sum * inv;
    const float var  = fmaf(sumsq, inv, -mu * mu);
    const float rstd = rsqrtf(var + LN_EPS);

    // epilogue from registers: dense permuted per-instruction stores (coalesced)
    float* __restrict__ yo = out + (size_t)row * CDIM;
#pragma unroll
    for (int s = 0; s < NTILE; ++s) {
        const int eS0 = 128 * s + 2 * l31 - 1 + hh;
        const int eS1 = eS0 + 64;
        if ((unsigned)eS0 < CDIM) {
            yo[eS0] = fmaf((y0[s] - mu) * rstd, gamma[eS0], beta[eS0]);
        }
        if ((unsigned)eS1 < CDIM) {
            yo[eS1] = fmaf((y1[s] - mu) * rstd, gamma[eS1], beta[eS1]);
        }
    }
}

extern "C" void kernel_launch(void* const* d_in, const int* in_sizes, int n_in,
                              void* d_out, int out_size, void* d_ws, size_t ws_size,
                              hipStream_t stream) {
    const float* x     = (const float*)d_in[0];
    const float* Wup   = (const float*)d_in[1];
    const float* bup   = (const float*)d_in[2];
    const float* Wdown = (const float*)d_in[3];
    const float* bdown = (const float*)d_in[4];   // cancels in LayerNorm; unused
    const float* gamma = (const float*)d_in[5];
    const float* beta  = (const float*)d_in[6];
    float* out = (float*)d_out;
    (void)bdown;

    const int nrows = out_size / CDIM;                 // 11520 (divisible by 4)
    const int nblk  = nrows / ROWS_PER_BLOCK;          // 2880
    cvmc_kernel<<<nblk, THREADS, 0, stream>>>(x, Wup, bup, Wdown, bdown,
                                              gamma, beta, out);
}